// Round 8
// baseline (2749.228 us; speedup 1.0000x reference)
//
#include <hip/hip_runtime.h>

#define D 64
#define CAP 64   // max in-degree; deg ~ Poisson(16), P(>64) ~ 1e-19

// ---------------------------------------------------------------------------
// Round-8: SPLIT for attribution + remove structural waste.
// Cross-round evidence: fused gather+project is pinned at ~160us no matter
// what (r2 fp32=r3 bf16=r5=r7; ~2 loads in flight per wave), and ~140us of
// prep never showed in top-5 (r6 single-prep ~150us). So:
//   k_prep   = bucket + typed node list (NO pack: r2 proved fp32==bf16 gather)
//   k_gather = gather only, agg -> d_out in place (no weight loads)
//   k_project_typed = dense typed projection, 4 nodes/wave (weights 32/node)
// ---------------------------------------------------------------------------

__global__ __launch_bounds__(256) void k_prep(
    const int* __restrict__ node_type,
    const int* __restrict__ src, const int* __restrict__ dst,
    int* __restrict__ counts, int* __restrict__ slots,
    int* __restrict__ tcnt, int* __restrict__ tlist,
    int n_nodes, int n_edges)
{
    int idx = blockIdx.x * 256 + threadIdx.x;

    // edge bucket: fixed-capacity CSR
    if (idx < n_edges) {
        int d = dst[idx];
        int slot = atomicAdd(&counts[d], 1);
        if (slot < CAP) slots[(size_t)d * CAP + slot] = src[idx];
    }

    // per-type node list, wave-aggregated atomics (verified r6)
    int lane = threadIdx.x & 63;
    int mytype = (idx < n_nodes) ? node_type[idx] : -1;
    unsigned long long ltmask = (1ull << lane) - 1ull;
#pragma unroll
    for (int t = 0; t < 4; ++t) {
        unsigned long long m = __ballot(mytype == t);
        if (m != 0ull) {
            int leader = __ffsll((long long)m) - 1;
            int base = 0;
            if (lane == leader) base = atomicAdd(&tcnt[t], __popcll(m));
            base = __shfl(base, leader);
            if (mytype == t)
                tlist[(size_t)t * n_nodes + base + __popcll(m & ltmask)] = idx;
        }
    }
}

// Gather only. 1 wave per node, all 64 lanes on the same edge:
// lane ch=lane>>4 (0=x,1..3=vec rows), q=lane&15 -> one float4 per lane
// covers the full 256-float row. 8 edges batched in flight. agg -> d_out.
__global__ __launch_bounds__(256) void k_gather(
    const float* __restrict__ x, const float* __restrict__ vec,
    const int* __restrict__ counts, const int* __restrict__ slots,
    float* __restrict__ out_s, float* __restrict__ out_v, int n_nodes)
{
    int wave = threadIdx.x >> 6, lane = threadIdx.x & 63;
    int n = blockIdx.x * 4 + wave;
    if (n >= n_nodes) return;
    int ch = lane >> 4, q = lane & 15;

    int cnt = counts[n]; if (cnt > CAP) cnt = CAP;
    int myidx = slots[(size_t)n * CAP + lane];   // one 256B wave load

    bool isx = (ch == 0);
    const float4* bp = isx ? (const float4*)x : (const float4*)vec;
    int stride4 = isx ? 16 : 48;
    int off4 = isx ? q : (ch - 1) * 16 + q;

    float4 acc = make_float4(0.f, 0.f, 0.f, 0.f);
    int k = 0;
    for (; k + 8 <= cnt; k += 8) {
        int s0 = __shfl(myidx, k);
        int s1 = __shfl(myidx, k + 1);
        int s2 = __shfl(myidx, k + 2);
        int s3 = __shfl(myidx, k + 3);
        int s4 = __shfl(myidx, k + 4);
        int s5 = __shfl(myidx, k + 5);
        int s6 = __shfl(myidx, k + 6);
        int s7 = __shfl(myidx, k + 7);
        float4 f0 = bp[(size_t)s0 * stride4 + off4];
        float4 f1 = bp[(size_t)s1 * stride4 + off4];
        float4 f2 = bp[(size_t)s2 * stride4 + off4];
        float4 f3 = bp[(size_t)s3 * stride4 + off4];
        float4 f4 = bp[(size_t)s4 * stride4 + off4];
        float4 f5 = bp[(size_t)s5 * stride4 + off4];
        float4 f6 = bp[(size_t)s6 * stride4 + off4];
        float4 f7 = bp[(size_t)s7 * stride4 + off4];
        acc.x += f0.x + f1.x + f2.x + f3.x + f4.x + f5.x + f6.x + f7.x;
        acc.y += f0.y + f1.y + f2.y + f3.y + f4.y + f5.y + f6.y + f7.y;
        acc.z += f0.z + f1.z + f2.z + f3.z + f4.z + f5.z + f6.z + f7.z;
        acc.w += f0.w + f1.w + f2.w + f3.w + f4.w + f5.w + f6.w + f7.w;
    }
    for (; k < cnt; ++k) {
        int s = __shfl(myidx, k);
        float4 f = bp[(size_t)s * stride4 + off4];
        acc.x += f.x; acc.y += f.y; acc.z += f.z; acc.w += f.w;
    }

    // in-place staging: agg row -> d_out (projection rewrites it later)
    if (isx) ((float4*)(out_s + (size_t)n * D))[q] = acc;
    else     ((float4*)(out_v + (size_t)n * 3 * D))[(ch - 1) * 16 + q] = acc;
}

// Dense typed projection, in place on d_out.
// Block = 16 nodes of ONE type (4 waves x 4 nodes). Per wave: 4 nodes' agg
// rows in registers (float a[4][4]: elem e of node g at lane e>>2 comp e&3
// for e<64 i.e. scalar ch; vec ch c at lane 16*(c)+ ... see mapping below),
// weight loads batched and amortized over 4 nodes (32 loads/node vs 128).
__global__ __launch_bounds__(256) void k_project_typed(
    const float* __restrict__ W_s, const float* __restrict__ W_v,
    const int* __restrict__ tcnt, const int* __restrict__ tlist,
    float* __restrict__ out_s, float* __restrict__ out_v, int n_nodes)
{
    int c0 = (tcnt[0] + 15) >> 4, c1 = (tcnt[1] + 15) >> 4;
    int c2 = (tcnt[2] + 15) >> 4, c3 = (tcnt[3] + 15) >> 4;
    int b = blockIdx.x, t, gi;
    if      (b < c0)                { t = 0; gi = b; }
    else if (b < c0 + c1)           { t = 1; gi = b - c0; }
    else if (b < c0 + c1 + c2)      { t = 2; gi = b - (c0 + c1); }
    else if (b < c0 + c1 + c2 + c3) { t = 3; gi = b - (c0 + c1 + c2); }
    else return;

    int wave = threadIdx.x >> 6, lane = threadIdx.x & 63;
    int nt = tcnt[t];

    // this wave's 4 nodes (may be < 4 valid at the type tail)
    int nn[4]; bool vld[4];
#pragma unroll
    for (int g = 0; g < 4; ++g) {
        int ni = gi * 16 + wave * 4 + g;
        vld[g] = (ni < nt);
        nn[g] = vld[g] ? tlist[(size_t)t * n_nodes + ni] : 0;
    }

    // load agg rows: lane l holds elems [4l,4l+4) of the 256-row:
    //   l in [0,16):  out_s[n][4l .. 4l+4)          (scalar ch, i = 4l..)
    //   l in [16,64): out_v[n][(l-16)*4 ..)         (vec chans)
    float a[4][4];
#pragma unroll
    for (int g = 0; g < 4; ++g) {
        const float* p = (lane < 16)
            ? out_s + (size_t)nn[g] * D + lane * 4
            : out_v + (size_t)nn[g] * 3 * D + (lane - 16) * 4;
        float4 f = *(const float4*)p;
        a[g][0] = f.x; a[g][1] = f.y; a[g][2] = f.z; a[g][3] = f.w;
    }

    const float* Ws = W_s + (size_t)t * D * D + lane;
    const float* Wv = W_v + (size_t)t * D * D + lane;

    float acc[4][4];
#pragma unroll
    for (int g = 0; g < 4; ++g)
#pragma unroll
        for (int c = 0; c < 4; ++c) acc[g][c] = 0.f;

#pragma unroll
    for (int ib = 0; ib < 8; ++ib) {
        float ws[8], wv[8];
#pragma unroll
        for (int u = 0; u < 8; ++u) {
            ws[u] = Ws[(ib * 8 + u) * D];   // coalesced 256B wave loads
            wv[u] = Wv[(ib * 8 + u) * D];
        }
#pragma unroll
        for (int u = 0; u < 8; ++u) {
            int i = ib * 8 + u;             // contraction index, compile-time
#pragma unroll
            for (int g = 0; g < 4; ++g) {
                // agg elem c*64+i lives at lane 16*c + (i>>2), comp i&3
                float as  = __shfl(a[g][i & 3],      (i >> 2));
                float av0 = __shfl(a[g][i & 3], 16 + (i >> 2));
                float av1 = __shfl(a[g][i & 3], 32 + (i >> 2));
                float av2 = __shfl(a[g][i & 3], 48 + (i >> 2));
                acc[g][0] = fmaf(as,  ws[u], acc[g][0]);
                acc[g][1] = fmaf(av0, wv[u], acc[g][1]);
                acc[g][2] = fmaf(av1, wv[u], acc[g][2]);
                acc[g][3] = fmaf(av2, wv[u], acc[g][3]);
            }
        }
    }

#pragma unroll
    for (int g = 0; g < 4; ++g) {
        if (!vld[g]) continue;
        out_s[(size_t)nn[g] * D + lane] = acc[g][0];
        float* ov = out_v + (size_t)nn[g] * 3 * D;
        ov[lane] = acc[g][1]; ov[D + lane] = acc[g][2]; ov[2 * D + lane] = acc[g][3];
    }
}

extern "C" void kernel_launch(void* const* d_in, const int* in_sizes, int n_in,
                              void* d_out, int out_size, void* d_ws, size_t ws_size,
                              hipStream_t stream) {
    const float* x         = (const float*)d_in[0];
    const float* vec       = (const float*)d_in[1];
    const int*   node_type = (const int*)d_in[2];
    const int*   src       = (const int*)d_in[3];
    const int*   dst       = (const int*)d_in[4];
    const float* W_s       = (const float*)d_in[5];
    const float* W_v       = (const float*)d_in[6];

    int n_nodes = in_sizes[2];
    int n_edges = in_sizes[3];

    float* out_s = (float*)d_out;
    float* out_v = out_s + (size_t)n_nodes * D;

    // ws layout (ints): [slots N*CAP][tlist 4N][counts N][tcnt 4]
    int* slots  = (int*)d_ws;
    int* tlist  = slots + (size_t)n_nodes * CAP;
    int* counts = tlist + (size_t)n_nodes * 4;
    int* tcnt   = counts + n_nodes;

    // zero counts + tcnt (contiguous, ~200KB)
    (void)hipMemsetAsync(counts, 0, (size_t)(n_nodes + 4) * sizeof(int), stream);

    int eb = (n_edges + 255) / 256;
    k_prep<<<eb, 256, 0, stream>>>(node_type, src, dst,
                                   counts, slots, tcnt, tlist, n_nodes, n_edges);

    k_gather<<<(n_nodes + 3) / 4, 256, 0, stream>>>(
        x, vec, counts, slots, out_s, out_v, n_nodes);

    k_project_typed<<<(n_nodes + 15) / 16 + 3, 256, 0, stream>>>(
        W_s, W_v, tcnt, tlist, out_s, out_v, n_nodes);
}

// Round 9
// 407.771 us; speedup vs baseline: 6.7421x; 6.7421x over previous
//
#include <hip/hip_runtime.h>

#define D 64
#define CAP 64   // max in-degree; deg ~ Poisson(16), P(>64) ~ 1e-19

// ---------------------------------------------------------------------------
// Round-9: r8 split was correct (absmax 0.0625) but k_project_typed spilled
// (VGPR=256, 3GB scratch traffic -> 2.5ms). Replace projection with the
// r7-proven no-spill inner loop (1 node/wave, 8-batched weight loads,
// ~44 VGPR) + type-batched blocks so W_s[t]+W_v[t] (32KB fp32) stay
// L1-resident -> removes the ~1.6GB of L2 weight-line traffic that the
// cross-round model says has been the fused-kernel ceiling all along.
// ---------------------------------------------------------------------------

__global__ __launch_bounds__(256) void k_prep(
    const int* __restrict__ node_type,
    const int* __restrict__ src, const int* __restrict__ dst,
    int* __restrict__ counts, int* __restrict__ slots,
    int* __restrict__ tcnt, int* __restrict__ tlist,
    int n_nodes, int n_edges)
{
    int idx = blockIdx.x * 256 + threadIdx.x;

    // edge bucket: fixed-capacity CSR
    if (idx < n_edges) {
        int d = dst[idx];
        int slot = atomicAdd(&counts[d], 1);
        if (slot < CAP) slots[(size_t)d * CAP + slot] = src[idx];
    }

    // per-type node list, wave-aggregated atomics (verified r6/r8)
    int lane = threadIdx.x & 63;
    int mytype = (idx < n_nodes) ? node_type[idx] : -1;
    unsigned long long ltmask = (1ull << lane) - 1ull;
#pragma unroll
    for (int t = 0; t < 4; ++t) {
        unsigned long long m = __ballot(mytype == t);
        if (m != 0ull) {
            int leader = __ffsll((long long)m) - 1;
            int base = 0;
            if (lane == leader) base = atomicAdd(&tcnt[t], __popcll(m));
            base = __shfl(base, leader);
            if (mytype == t)
                tlist[(size_t)t * n_nodes + base + __popcll(m & ltmask)] = idx;
        }
    }
}

// Gather only (verified r8). 1 wave/node, all 64 lanes on the same edge:
// lane ch=lane>>4 (0=x,1..3=vec rows), q=lane&15 -> one float4 per lane
// covers the full 256-float row. 8 edges batched in flight. agg -> d_out.
__global__ __launch_bounds__(256) void k_gather(
    const float* __restrict__ x, const float* __restrict__ vec,
    const int* __restrict__ counts, const int* __restrict__ slots,
    float* __restrict__ out_s, float* __restrict__ out_v, int n_nodes)
{
    int wave = threadIdx.x >> 6, lane = threadIdx.x & 63;
    int n = blockIdx.x * 4 + wave;
    if (n >= n_nodes) return;
    int ch = lane >> 4, q = lane & 15;

    int cnt = counts[n]; if (cnt > CAP) cnt = CAP;
    int myidx = slots[(size_t)n * CAP + lane];   // one 256B wave load

    bool isx = (ch == 0);
    const float4* bp = isx ? (const float4*)x : (const float4*)vec;
    int stride4 = isx ? 16 : 48;
    int off4 = isx ? q : (ch - 1) * 16 + q;

    float4 acc = make_float4(0.f, 0.f, 0.f, 0.f);
    int k = 0;
    for (; k + 8 <= cnt; k += 8) {
        int s0 = __shfl(myidx, k);
        int s1 = __shfl(myidx, k + 1);
        int s2 = __shfl(myidx, k + 2);
        int s3 = __shfl(myidx, k + 3);
        int s4 = __shfl(myidx, k + 4);
        int s5 = __shfl(myidx, k + 5);
        int s6 = __shfl(myidx, k + 6);
        int s7 = __shfl(myidx, k + 7);
        float4 f0 = bp[(size_t)s0 * stride4 + off4];
        float4 f1 = bp[(size_t)s1 * stride4 + off4];
        float4 f2 = bp[(size_t)s2 * stride4 + off4];
        float4 f3 = bp[(size_t)s3 * stride4 + off4];
        float4 f4 = bp[(size_t)s4 * stride4 + off4];
        float4 f5 = bp[(size_t)s5 * stride4 + off4];
        float4 f6 = bp[(size_t)s6 * stride4 + off4];
        float4 f7 = bp[(size_t)s7 * stride4 + off4];
        acc.x += f0.x + f1.x + f2.x + f3.x + f4.x + f5.x + f6.x + f7.x;
        acc.y += f0.y + f1.y + f2.y + f3.y + f4.y + f5.y + f6.y + f7.y;
        acc.z += f0.z + f1.z + f2.z + f3.z + f4.z + f5.z + f6.z + f7.z;
        acc.w += f0.w + f1.w + f2.w + f3.w + f4.w + f5.w + f6.w + f7.w;
    }
    for (; k < cnt; ++k) {
        int s = __shfl(myidx, k);
        float4 f = bp[(size_t)s * stride4 + off4];
        acc.x += f.x; acc.y += f.y; acc.z += f.z; acc.w += f.w;
    }

    // in-place staging: agg row -> d_out (projection rewrites it later)
    if (isx) ((float4*)(out_s + (size_t)n * D))[q] = acc;
    else     ((float4*)(out_v + (size_t)n * 3 * D))[(ch - 1) * 16 + q] = acc;
}

// Typed projection, in place on d_out. Block = 4 nodes of ONE type
// (1 node/wave -> the r7-proven no-spill loop). Weight loads 8-batched,
// L1-resident because consecutive blocks share the type.
// agg elem mapping (verified r8): 256-row elem e at lane e>>2, comp e&3;
// scalar i -> lane i>>2; vec ch c elem i -> lane 16*(c+1)+(i>>2).
__global__ __launch_bounds__(256) void k_project(
    const float* __restrict__ W_s, const float* __restrict__ W_v,
    const int* __restrict__ tcnt, const int* __restrict__ tlist,
    float* __restrict__ out_s, float* __restrict__ out_v, int n_nodes)
{
    int c0 = (tcnt[0] + 3) >> 2, c1 = (tcnt[1] + 3) >> 2;
    int c2 = (tcnt[2] + 3) >> 2, c3 = (tcnt[3] + 3) >> 2;
    int b = blockIdx.x, t, gi;
    if      (b < c0)                { t = 0; gi = b; }
    else if (b < c0 + c1)           { t = 1; gi = b - c0; }
    else if (b < c0 + c1 + c2)      { t = 2; gi = b - (c0 + c1); }
    else if (b < c0 + c1 + c2 + c3) { t = 3; gi = b - (c0 + c1 + c2); }
    else return;

    int wave = threadIdx.x >> 6, lane = threadIdx.x & 63;
    int ni = gi * 4 + wave;
    if (ni >= tcnt[t]) return;
    int n = tlist[(size_t)t * n_nodes + ni];

    // load agg row: lane l holds elems [4l, 4l+4) of the 256-row
    const float* p = (lane < 16)
        ? out_s + (size_t)n * D + lane * 4
        : out_v + (size_t)n * 3 * D + (lane - 16) * 4;
    float4 f = *(const float4*)p;
    float a[4] = {f.x, f.y, f.z, f.w};

    const float* Ws = W_s + (size_t)t * D * D + lane;
    const float* Wv = W_v + (size_t)t * D * D + lane;

    float ys = 0.f, y0 = 0.f, y1 = 0.f, y2 = 0.f;
#pragma unroll
    for (int ib = 0; ib < 8; ++ib) {
        float ws[8], wv[8];
#pragma unroll
        for (int u = 0; u < 8; ++u) {
            ws[u] = Ws[(ib * 8 + u) * D];   // coalesced 256B, L1-hot
            wv[u] = Wv[(ib * 8 + u) * D];
        }
#pragma unroll
        for (int u = 0; u < 8; ++u) {
            int i = ib * 8 + u;             // compile-time lane indices
            float as  = __shfl(a[i & 3],      (i >> 2));
            float av0 = __shfl(a[i & 3], 16 + (i >> 2));
            float av1 = __shfl(a[i & 3], 32 + (i >> 2));
            float av2 = __shfl(a[i & 3], 48 + (i >> 2));
            ys = fmaf(as,  ws[u], ys);
            y0 = fmaf(av0, wv[u], y0);
            y1 = fmaf(av1, wv[u], y1);
            y2 = fmaf(av2, wv[u], y2);
        }
    }
    out_s[(size_t)n * D + lane] = ys;
    float* ov = out_v + (size_t)n * 3 * D;
    ov[lane] = y0; ov[D + lane] = y1; ov[2 * D + lane] = y2;
}

extern "C" void kernel_launch(void* const* d_in, const int* in_sizes, int n_in,
                              void* d_out, int out_size, void* d_ws, size_t ws_size,
                              hipStream_t stream) {
    const float* x         = (const float*)d_in[0];
    const float* vec       = (const float*)d_in[1];
    const int*   node_type = (const int*)d_in[2];
    const int*   src       = (const int*)d_in[3];
    const int*   dst       = (const int*)d_in[4];
    const float* W_s       = (const float*)d_in[5];
    const float* W_v       = (const float*)d_in[6];

    int n_nodes = in_sizes[2];
    int n_edges = in_sizes[3];

    float* out_s = (float*)d_out;
    float* out_v = out_s + (size_t)n_nodes * D;

    // ws layout (ints): [slots N*CAP][tlist 4N][counts N][tcnt 4]
    int* slots  = (int*)d_ws;
    int* tlist  = slots + (size_t)n_nodes * CAP;
    int* counts = tlist + (size_t)n_nodes * 4;
    int* tcnt   = counts + n_nodes;

    // zero counts + tcnt (contiguous, ~200KB)
    (void)hipMemsetAsync(counts, 0, (size_t)(n_nodes + 4) * sizeof(int), stream);

    int eb = (n_edges + 255) / 256;
    k_prep<<<eb, 256, 0, stream>>>(node_type, src, dst,
                                   counts, slots, tcnt, tlist, n_nodes, n_edges);

    k_gather<<<(n_nodes + 3) / 4, 256, 0, stream>>>(
        x, vec, counts, slots, out_s, out_v, n_nodes);

    k_project<<<(n_nodes + 3) / 4 + 3, 256, 0, stream>>>(
        W_s, W_v, tcnt, tlist, out_s, out_v, n_nodes);
}

// Round 10
// 332.420 us; speedup vs baseline: 8.2703x; 1.2267x over previous
//
#include <hip/hip_runtime.h>

#define D 64
#define CAP 64   // max in-degree; deg ~ Poisson(16), P(>64) ~ 1e-19

// ---------------------------------------------------------------------------
// Round-10: per-CU VMEM-instruction-throughput model (~15 cyc per wave64 VMEM
// op/CU, fits r2/r3/r5/r7/r9). k_project rewritten to cut VMEM instrs
// 133 -> ~37: float4 weight loads (1KB/instr: lanes cover rows 4u..4u+3 x all
// 64 cols), dynamic-bpermute agg broadcast, xor-reduce over row-groups,
// single predicated float4 store. prep/gather unchanged (A/B attribution).
// ---------------------------------------------------------------------------

__global__ __launch_bounds__(256) void k_prep(
    const int* __restrict__ node_type,
    const int* __restrict__ src, const int* __restrict__ dst,
    int* __restrict__ counts, int* __restrict__ slots,
    int* __restrict__ tcnt, int* __restrict__ tlist,
    int n_nodes, int n_edges)
{
    int idx = blockIdx.x * 256 + threadIdx.x;

    if (idx < n_edges) {
        int d = dst[idx];
        int slot = atomicAdd(&counts[d], 1);
        if (slot < CAP) slots[(size_t)d * CAP + slot] = src[idx];
    }

    int lane = threadIdx.x & 63;
    int mytype = (idx < n_nodes) ? node_type[idx] : -1;
    unsigned long long ltmask = (1ull << lane) - 1ull;
#pragma unroll
    for (int t = 0; t < 4; ++t) {
        unsigned long long m = __ballot(mytype == t);
        if (m != 0ull) {
            int leader = __ffsll((long long)m) - 1;
            int base = 0;
            if (lane == leader) base = atomicAdd(&tcnt[t], __popcll(m));
            base = __shfl(base, leader);
            if (mytype == t)
                tlist[(size_t)t * n_nodes + base + __popcll(m & ltmask)] = idx;
        }
    }
}

// Gather (verified r8/r9): 1 wave/node, lane ch=lane>>4, q=lane&15 -> one
// float4/lane covers the 256-float row; 8 edges batched; agg -> d_out.
__global__ __launch_bounds__(256) void k_gather(
    const float* __restrict__ x, const float* __restrict__ vec,
    const int* __restrict__ counts, const int* __restrict__ slots,
    float* __restrict__ out_s, float* __restrict__ out_v, int n_nodes)
{
    int wave = threadIdx.x >> 6, lane = threadIdx.x & 63;
    int n = blockIdx.x * 4 + wave;
    if (n >= n_nodes) return;
    int ch = lane >> 4, q = lane & 15;

    int cnt = counts[n]; if (cnt > CAP) cnt = CAP;
    int myidx = slots[(size_t)n * CAP + lane];

    bool isx = (ch == 0);
    const float4* bp = isx ? (const float4*)x : (const float4*)vec;
    int stride4 = isx ? 16 : 48;
    int off4 = isx ? q : (ch - 1) * 16 + q;

    float4 acc = make_float4(0.f, 0.f, 0.f, 0.f);
    int k = 0;
    for (; k + 8 <= cnt; k += 8) {
        int s0 = __shfl(myidx, k);
        int s1 = __shfl(myidx, k + 1);
        int s2 = __shfl(myidx, k + 2);
        int s3 = __shfl(myidx, k + 3);
        int s4 = __shfl(myidx, k + 4);
        int s5 = __shfl(myidx, k + 5);
        int s6 = __shfl(myidx, k + 6);
        int s7 = __shfl(myidx, k + 7);
        float4 f0 = bp[(size_t)s0 * stride4 + off4];
        float4 f1 = bp[(size_t)s1 * stride4 + off4];
        float4 f2 = bp[(size_t)s2 * stride4 + off4];
        float4 f3 = bp[(size_t)s3 * stride4 + off4];
        float4 f4 = bp[(size_t)s4 * stride4 + off4];
        float4 f5 = bp[(size_t)s5 * stride4 + off4];
        float4 f6 = bp[(size_t)s6 * stride4 + off4];
        float4 f7 = bp[(size_t)s7 * stride4 + off4];
        acc.x += f0.x + f1.x + f2.x + f3.x + f4.x + f5.x + f6.x + f7.x;
        acc.y += f0.y + f1.y + f2.y + f3.y + f4.y + f5.y + f6.y + f7.y;
        acc.z += f0.z + f1.z + f2.z + f3.z + f4.z + f5.z + f6.z + f7.z;
        acc.w += f0.w + f1.w + f2.w + f3.w + f4.w + f5.w + f6.w + f7.w;
    }
    for (; k < cnt; ++k) {
        int s = __shfl(myidx, k);
        float4 f = bp[(size_t)s * stride4 + off4];
        acc.x += f.x; acc.y += f.y; acc.z += f.z; acc.w += f.w;
    }

    if (isx) ((float4*)(out_s + (size_t)n * D))[q] = acc;
    else     ((float4*)(out_v + (size_t)n * 3 * D))[(ch - 1) * 16 + q] = acc;
}

// Typed projection v3, in place on d_out. 1 node/wave, 4 nodes/block,
// type-batched blocks (weights L1-hot — r9 FETCH 26MB proved it).
// VMEM per wave: 4 agg loads + 32 x 1KB weight loads + 1 store = 37
// (vs r9's 133; model predicts ~2.7x faster).
__global__ __launch_bounds__(256) void k_project(
    const float* __restrict__ W_s, const float* __restrict__ W_v,
    const int* __restrict__ tcnt, const int* __restrict__ tlist,
    float* __restrict__ out_s, float* __restrict__ out_v, int n_nodes)
{
    int c0 = (tcnt[0] + 3) >> 2, c1 = (tcnt[1] + 3) >> 2;
    int c2 = (tcnt[2] + 3) >> 2, c3 = (tcnt[3] + 3) >> 2;
    int b = blockIdx.x, t, gi;
    if      (b < c0)                { t = 0; gi = b; }
    else if (b < c0 + c1)           { t = 1; gi = b - c0; }
    else if (b < c0 + c1 + c2)      { t = 2; gi = b - (c0 + c1); }
    else if (b < c0 + c1 + c2 + c3) { t = 3; gi = b - (c0 + c1 + c2); }
    else return;

    int wave = threadIdx.x >> 6, lane = threadIdx.x & 63;
    int ni = gi * 4 + wave;
    if (ni >= tcnt[t]) return;
    int n = tlist[(size_t)t * n_nodes + ni];

    int h = lane >> 4, q = lane & 15;   // h: row-group, q: column-group

    // agg row, natural layout: elem c*64+i at lane i, component c
    float a0 = out_s[(size_t)n * D + lane];
    const float* ovi = out_v + (size_t)n * 3 * D;
    float a1 = ovi[lane];
    float a2 = ovi[D + lane];
    float a3 = ovi[2 * D + lane];

    // lane (h,q): columns 4q..4q+3, rows i = 4u+h (u=0..15).
    // Per u the wave loads W rows 4u..4u+3 complete = 1KB contiguous.
    const float* WsB = W_s + (size_t)t * D * D + h * D + q * 4;
    const float* WvB = W_v + (size_t)t * D * D + h * D + q * 4;

    float ys[4] = {0,0,0,0}, y0[4] = {0,0,0,0};
    float y1[4] = {0,0,0,0}, y2[4] = {0,0,0,0};
#pragma unroll
    for (int u = 0; u < 16; ++u) {
        int i = 4 * u + h;                 // this lane's row (dynamic shfl src)
        float b0 = __shfl(a0, i);
        float b1 = __shfl(a1, i);
        float b2 = __shfl(a2, i);
        float b3 = __shfl(a3, i);
        float4 ws = *(const float4*)(WsB + (size_t)u * 4 * D);
        float4 wv = *(const float4*)(WvB + (size_t)u * 4 * D);
        ys[0] = fmaf(b0, ws.x, ys[0]); ys[1] = fmaf(b0, ws.y, ys[1]);
        ys[2] = fmaf(b0, ws.z, ys[2]); ys[3] = fmaf(b0, ws.w, ys[3]);
        y0[0] = fmaf(b1, wv.x, y0[0]); y0[1] = fmaf(b1, wv.y, y0[1]);
        y0[2] = fmaf(b1, wv.z, y0[2]); y0[3] = fmaf(b1, wv.w, y0[3]);
        y1[0] = fmaf(b2, wv.x, y1[0]); y1[1] = fmaf(b2, wv.y, y1[1]);
        y1[2] = fmaf(b2, wv.z, y1[2]); y1[3] = fmaf(b2, wv.w, y1[3]);
        y2[0] = fmaf(b3, wv.x, y2[0]); y2[1] = fmaf(b3, wv.y, y2[1]);
        y2[2] = fmaf(b3, wv.z, y2[2]); y2[3] = fmaf(b3, wv.w, y2[3]);
    }

    // reduce over h (lanes differing in bits 4,5); all lanes end with full sums
#pragma unroll
    for (int m = 16; m <= 32; m <<= 1) {
#pragma unroll
        for (int c = 0; c < 4; ++c) {
            ys[c] += __shfl_xor(ys[c], m);
            y0[c] += __shfl_xor(y0[c], m);
            y1[c] += __shfl_xor(y1[c], m);
            y2[c] += __shfl_xor(y2[c], m);
        }
    }

    // store: lane (h,q) writes channel h, columns 4q..4q+3 — ONE float4 store
    // (out_s and out_v live in the same d_out buffer).
    float* dstp = (h == 0) ? out_s + (size_t)n * D + q * 4
                           : out_v + (size_t)n * 3 * D + (h - 1) * D + q * 4;
    float4 r;
    if      (h == 0) r = make_float4(ys[0], ys[1], ys[2], ys[3]);
    else if (h == 1) r = make_float4(y0[0], y0[1], y0[2], y0[3]);
    else if (h == 2) r = make_float4(y1[0], y1[1], y1[2], y1[3]);
    else             r = make_float4(y2[0], y2[1], y2[2], y2[3]);
    *(float4*)dstp = r;
}

extern "C" void kernel_launch(void* const* d_in, const int* in_sizes, int n_in,
                              void* d_out, int out_size, void* d_ws, size_t ws_size,
                              hipStream_t stream) {
    const float* x         = (const float*)d_in[0];
    const float* vec       = (const float*)d_in[1];
    const int*   node_type = (const int*)d_in[2];
    const int*   src       = (const int*)d_in[3];
    const int*   dst       = (const int*)d_in[4];
    const float* W_s       = (const float*)d_in[5];
    const float* W_v       = (const float*)d_in[6];

    int n_nodes = in_sizes[2];
    int n_edges = in_sizes[3];

    float* out_s = (float*)d_out;
    float* out_v = out_s + (size_t)n_nodes * D;

    // ws layout (ints): [slots N*CAP][tlist 4N][counts N][tcnt 4]
    int* slots  = (int*)d_ws;
    int* tlist  = slots + (size_t)n_nodes * CAP;
    int* counts = tlist + (size_t)n_nodes * 4;
    int* tcnt   = counts + n_nodes;

    (void)hipMemsetAsync(counts, 0, (size_t)(n_nodes + 4) * sizeof(int), stream);

    int eb = (n_edges + 255) / 256;
    k_prep<<<eb, 256, 0, stream>>>(node_type, src, dst,
                                   counts, slots, tcnt, tlist, n_nodes, n_edges);

    k_gather<<<(n_nodes + 3) / 4, 256, 0, stream>>>(
        x, vec, counts, slots, out_s, out_v, n_nodes);

    k_project<<<(n_nodes + 3) / 4 + 3, 256, 0, stream>>>(
        W_s, W_v, tcnt, tlist, out_s, out_v, n_nodes);
}